// Round 6
// baseline (233.017 us; speedup 1.0000x reference)
//
#include <hip/hip_runtime.h>
#include <stdint.h>

typedef unsigned short u16;
typedef __bf16 bf16x8 __attribute__((ext_vector_type(8)));
typedef float f32x4 __attribute__((ext_vector_type(4)));

#define B_ 2
#define T_ 2048

// ---------- helpers ----------
__device__ __forceinline__ u16 f2b(float f) {
  unsigned u = __float_as_uint(f);
  u += 0x7fffu + ((u >> 16) & 1u);
  return (u16)(u >> 16);
}
__device__ __forceinline__ float b2f(u16 v) {
  return __uint_as_float(((unsigned)v) << 16);
}
__device__ __forceinline__ unsigned cvt_pk(float lo, float hi) {
  unsigned r;
  asm("v_cvt_pk_bf16_f32 %0, %1, %2" : "=v"(r) : "v"(lo), "v"(hi));
  return r;
}
__device__ __forceinline__ float ex2(float x) {  // 2^x
  float r;
  asm("v_exp_f32 %0, %1" : "=v"(r) : "v"(x));
  return r;
}

using gu32 = __attribute__((address_space(1))) const unsigned int;
using lu32 = __attribute__((address_space(3))) unsigned int;
__device__ __forceinline__ void gl_lds16(const u16* g, u16* l) {
  __builtin_amdgcn_global_load_lds((gu32*)g, (lu32*)l, 16, 0, 0);
}

// ---------- convert x fp32 -> bf16 ----------
__global__ __launch_bounds__(256) void conv_x_kernel(const float* __restrict__ in,
                                                     u16* __restrict__ out) {
  int i = (blockIdx.x * 256 + threadIdx.x) * 4;
  float4 v = *reinterpret_cast<const float4*>(in + i);
  union { u16 h[4]; unsigned long long ll; } pk;
  pk.h[0] = f2b(v.x); pk.h[1] = f2b(v.y); pk.h[2] = f2b(v.z); pk.h[3] = f2b(v.w);
  *reinterpret_cast<unsigned long long*>(out + i) = pk.ll;
}

// ---------- fused all-weight transpose: fp32 [K][N] -> bf16 Wt[row_off+n][k] ----------
struct TJob { const float* src; u16* dst; int K, N, ldt, row_off, blk0; };
struct TJobs { TJob j[7]; };

__global__ __launch_bounds__(256) void transpose_all_kernel(TJobs jobs) {
  __shared__ float tile[32][33];
  int bid = blockIdx.x;
  int ji = 0;
  #pragma unroll
  for (int i = 6; i > 0; --i)
    if (bid >= jobs.j[i].blk0) { ji = i; break; }
  const TJob jb = jobs.j[ji];
  int local = bid - jb.blk0;
  int nb = jb.N >> 5;
  int n0 = (local % nb) * 32, k0 = (local / nb) * 32;
  int cx = threadIdx.x, ry = threadIdx.y;
  #pragma unroll
  for (int i = 0; i < 4; i++)
    tile[ry + i * 8][cx] = jb.src[(size_t)(k0 + ry + i * 8) * jb.N + n0 + cx];
  __syncthreads();
  #pragma unroll
  for (int i = 0; i < 4; i++)
    jb.dst[(size_t)(jb.row_off + n0 + ry + i * 8) * jb.ldt + k0 + cx] =
        f2b(tile[cx][ry + i * 8]);
}

// ---------- GEMM (2-phase dbuf, counted vmcnt) with fused epilogues ----------
// mode: 0 = bf16 out; 1 = f32 out; 2 = kvo (VT copy col<1024, rope col>=1024);
//       3 = qo (rope col>=1024)
__global__ __launch_bounds__(256) void gemm_bt(const u16* __restrict__ A, int lda,
                                               const u16* __restrict__ Bt, int ldb,
                                               void* __restrict__ Cout, int ldc,
                                               int K, int mode, u16* __restrict__ vt,
                                               const float* __restrict__ cosT,
                                               const float* __restrict__ sinT) {
  __shared__ u16 As[2][128 * 32];
  __shared__ u16 Bs[2][128 * 32];
  const int tid = threadIdx.x;
  const int wave = tid >> 6, lane = tid & 63;
  const int wr = wave >> 1, wc = wave & 1;
  const int l15 = lane & 15, l4 = lane >> 4;
  const int m0 = blockIdx.y * 128, n0 = blockIdx.x * 128;
  const int lr = lane >> 2;
  const int lc = (lane & 3) * 8;

  f32x4 acc[4][4];
  const f32x4 fzero = {0.f, 0.f, 0.f, 0.f};
  #pragma unroll
  for (int m = 0; m < 4; m++)
    #pragma unroll
    for (int n = 0; n < 4; n++)
      acc[m][n] = fzero;

  const u16* gA  = A  + (size_t)(m0 + wave * 32 + lr) * lda + lc;
  const u16* gA2 = gA + (size_t)16 * lda;
  const u16* gB  = Bt + (size_t)(n0 + wave * 32 + lr) * ldb + lc;
  const u16* gB2 = gB + (size_t)16 * ldb;

  auto stage = [&](int buf, int k0) {
    gl_lds16(gA + k0, &As[buf][(wave * 32) * 32]);
    gl_lds16(gA2 + k0, &As[buf][(wave * 32 + 16) * 32]);
    gl_lds16(gB + k0, &Bs[buf][(wave * 32) * 32]);
    gl_lds16(gB2 + k0, &Bs[buf][(wave * 32 + 16) * 32]);
  };

  stage(0, 0);
  int buf = 0;
  for (int k0 = 0; k0 < K; k0 += 32) {
    const bool pre = (k0 + 32 < K);
    if (pre) stage(buf ^ 1, k0 + 32);
    // counted wait: keep the 4 just-issued prefetch loads in flight,
    // guarantee the previous stage (this tile) has landed in LDS.
    if (pre) { asm volatile("s_waitcnt vmcnt(4)" ::: "memory"); }
    else     { asm volatile("s_waitcnt vmcnt(0)" ::: "memory"); }
    __builtin_amdgcn_s_barrier();
    bf16x8 af[4], bfr[4];
    #pragma unroll
    for (int m = 0; m < 4; m++)
      af[m] = *reinterpret_cast<const bf16x8*>(&As[buf][(wr * 64 + m * 16 + l15) * 32 + l4 * 8]);
    #pragma unroll
    for (int n = 0; n < 4; n++)
      bfr[n] = *reinterpret_cast<const bf16x8*>(&Bs[buf][(wc * 64 + n * 16 + l15) * 32 + l4 * 8]);
    #pragma unroll
    for (int m = 0; m < 4; m++)
      #pragma unroll
      for (int n = 0; n < 4; n++)
        acc[m][n] = __builtin_amdgcn_mfma_f32_16x16x32_bf16(af[m], bfr[n], acc[m][n], 0, 0, 0);
    __builtin_amdgcn_s_barrier();   // protect LDS reuse; no vmcnt drain
    buf ^= 1;
  }

  const int row_base = m0 + wr * 64 + l4 * 4;
  const int col_base = n0 + wc * 64 + l15;

  if (mode == 1) {
    float* Cf = (float*)Cout;
    #pragma unroll
    for (int m = 0; m < 4; m++)
      #pragma unroll
      for (int n = 0; n < 4; n++)
        #pragma unroll
        for (int r = 0; r < 4; r++)
          Cf[(size_t)(row_base + m * 16 + r) * ldc + col_base + n * 16] = acc[m][n][r];
    return;
  }

  // fused rope on the rope half (cols >= 1024), in f32 before quantization.
  if (mode >= 2 && (n0 + wc * 64) >= 1024) {
    #pragma unroll
    for (int m = 0; m < 4; m++)
      #pragma unroll
      for (int r = 0; r < 4; r++) {
        int t = (row_base + m * 16 + r) & (T_ - 1);
        const float* cp = cosT + t * 64 + l15;
        const float* sp = sinT + t * 64 + l15;
        float c0 = cp[0], c16 = cp[16], c32 = cp[32], c48 = cp[48];
        float s0 = sp[0], s16 = sp[16], s32 = sp[32], s48 = sp[48];
        float x0 = acc[m][0][r], x1 = acc[m][1][r];
        float x2 = acc[m][2][r], x3 = acc[m][3][r];
        acc[m][0][r] = x0 * c0 - x2 * s0;
        acc[m][1][r] = x1 * c16 - x3 * s16;
        acc[m][2][r] = x2 * c32 + x0 * s32;
        acc[m][3][r] = x3 * c48 + x1 * s48;
      }
  }

  u16* Cb = (u16*)Cout;
  #pragma unroll
  for (int m = 0; m < 4; m++)
    #pragma unroll
    for (int n = 0; n < 4; n++)
      #pragma unroll
      for (int r = 0; r < 4; r++)
        Cb[(size_t)(row_base + m * 16 + r) * ldc + col_base + n * 16] = f2b(acc[m][n][r]);

  if (mode == 2) {
    // transposed copy of V content cols: VT[(b*1024+col)][t]
    #pragma unroll
    for (int m = 0; m < 4; m++)
      #pragma unroll
      for (int n = 0; n < 4; n++) {
        int col = col_base + n * 16;
        if (col < 1024) {
          int mm = row_base + m * 16;
          int bb = mm >> 11, tt = mm & 2047;
          uint2 pk2;
          pk2.x = cvt_pk(acc[m][n][0], acc[m][n][1]);
          pk2.y = cvt_pk(acc[m][n][2], acc[m][n][3]);
          *reinterpret_cast<uint2*>(&vt[(size_t)(bb * 1024 + col) * 2048 + tt]) = pk2;
        }
      }
  }
}

// ---------- causal flash attention: QBLK=128, 8 waves, counted vmcnt ----------
__global__ __launch_bounds__(512) void attn_kernel(const u16* __restrict__ qo,
                                                   const u16* __restrict__ kvo,
                                                   const u16* __restrict__ vtg,
                                                   u16* __restrict__ yb) {
  __shared__ u16 K_lds[2][64 * 128];   // rows swizzled: byte ^= (row&7)<<4
  __shared__ u16 V_lds[2][64 * 64];    // V^T, same swizzle
  __shared__ u16 P_lds[8][16][72];
  const int tid = threadIdx.x;
  const int wave = tid >> 6, lane = tid & 63;
  const int l15 = lane & 15, l4 = lane >> 4;
  const int bid = blockIdx.x;
  const int bh = bid & 31;
  const int qi = 15 - (bid >> 5);
  const int b = bh >> 4, h = bh & 15;
  const int q0 = qi * 128;
  const int qrow = q0 + wave * 16 + l15;

  const u16* qb = qo + (size_t)(b * T_ + qrow) * 2048 + h * 64;
  bf16x8 qf[4];
  qf[0] = *reinterpret_cast<const bf16x8*>(qb + l4 * 8);
  qf[1] = *reinterpret_cast<const bf16x8*>(qb + 32 + l4 * 8);
  qf[2] = *reinterpret_cast<const bf16x8*>(qb + 1024 + l4 * 8);
  qf[3] = *reinterpret_cast<const bf16x8*>(qb + 1056 + l4 * 8);

  const u16* Kbase = kvo + (size_t)(b * T_) * 2048 + h * 64;
  const u16* Vbase = vtg + (size_t)(b * 1024 + h * 64) * 2048;

  const int krow_i = lane >> 4;
  const int kc2 = (lane & 15) * 16;
  const int vrow_i = lane >> 3;
  const int vc2 = (lane & 7) * 16;

  auto stage = [&](int buf, int kv0) {
    #pragma unroll
    for (int j = 0; j < 2; j++) {
      int row = wave * 8 + j * 4 + krow_i;
      int c2x = kc2 ^ ((row & 7) << 4);
      int cu = c2x >> 1;
      const u16* src = Kbase + (size_t)(kv0 + row) * 2048 + (cu < 64 ? cu : 960 + cu);
      gl_lds16(src, &K_lds[buf][(wave * 8 + j * 4) * 128]);
    }
    {
      int row = wave * 8 + vrow_i;
      int c2x = vc2 ^ ((row & 7) << 4);
      const u16* src = Vbase + (size_t)row * 2048 + kv0 + (c2x >> 1);
      gl_lds16(src, &V_lds[buf][(wave * 8) * 64]);
    }
  };

  const f32x4 fzero = {0.f, 0.f, 0.f, 0.f};
  f32x4 oT[4];
  #pragma unroll
  for (int f = 0; f < 4; f++) oT[f] = fzero;
  float m_run = -1e30f, l_run = 0.f;

  const float SCALE2 = 0.125f * 1.44269504f;   // 1/sqrt(64) * log2(e)
  const int nt = qi * 2 + 2;
  const int t_diag = qi * 2 + (wave >> 2);

  stage(0, 0);
  int buf = 0;

  for (int t = 0; t < nt; t++) {
    const int kv0 = t * 64;
    const bool pre = (t + 1 < nt);
    if (pre) stage(buf ^ 1, kv0 + 64);
    // counted wait: 3 prefetch loads stay in flight; this tile's stage done.
    if (pre) { asm volatile("s_waitcnt vmcnt(3)" ::: "memory"); }
    else     { asm volatile("s_waitcnt vmcnt(0)" ::: "memory"); }
    __builtin_amdgcn_s_barrier();

    if (t <= t_diag) {
      const char* Kb = (const char*)&K_lds[buf][0];
      const char* Vb = (const char*)&V_lds[buf][0];

      f32x4 sT[4];
      #pragma unroll
      for (int c = 0; c < 4; c++) sT[c] = fzero;
      __builtin_amdgcn_s_setprio(1);
      #pragma unroll
      for (int c = 0; c < 4; c++) {
        const int krow = c * 16 + l15;
        const int kxm = (krow & 7) << 4;
        #pragma unroll
        for (int s = 0; s < 4; s++) {
          bf16x8 kf = *reinterpret_cast<const bf16x8*>(
              Kb + krow * 256 + ((s * 64 + l4 * 16) ^ kxm));
          sT[c] = __builtin_amdgcn_mfma_f32_16x16x32_bf16(kf, qf[s], sT[c], 0, 0, 0);
        }
      }
      __builtin_amdgcn_s_setprio(0);

      const bool diag = (t == t_diag);
      float p[4][4];
      float mx = -1e30f;
      #pragma unroll
      for (int c = 0; c < 4; c++)
        #pragma unroll
        for (int r = 0; r < 4; r++) {
          float s = sT[c][r] * SCALE2;
          if (diag) {
            int kv = kv0 + c * 16 + l4 * 4 + r;
            if (kv > qrow) s = -1e30f;
          }
          p[c][r] = s;
          mx = fmaxf(mx, s);
        }
      mx = fmaxf(mx, __shfl_xor(mx, 16));
      mx = fmaxf(mx, __shfl_xor(mx, 32));
      if (__any(mx > m_run + 11.5f)) {         // defer-max (T13)
        float m_new = fmaxf(m_run, mx);
        float corr = ex2(m_run - m_new);
        l_run *= corr;
        #pragma unroll
        for (int f = 0; f < 4; f++) oT[f] *= corr;
        m_run = m_new;
      }
      float rsum = 0.f;
      #pragma unroll
      for (int c = 0; c < 4; c++)
        #pragma unroll
        for (int r = 0; r < 4; r++) {
          float pe = ex2(p[c][r] - m_run);
          p[c][r] = pe;
          rsum += pe;
        }
      rsum += __shfl_xor(rsum, 16);
      rsum += __shfl_xor(rsum, 32);
      l_run += rsum;

      #pragma unroll
      for (int c = 0; c < 4; c++) {
        uint2 pk2;
        pk2.x = cvt_pk(p[c][0], p[c][1]);
        pk2.y = cvt_pk(p[c][2], p[c][3]);
        *reinterpret_cast<uint2*>(&P_lds[wave][l15][c * 16 + l4 * 4]) = pk2;
      }
      bf16x8 pb0 = *reinterpret_cast<const bf16x8*>(&P_lds[wave][l15][l4 * 8]);
      bf16x8 pb1 = *reinterpret_cast<const bf16x8*>(&P_lds[wave][l15][32 + l4 * 8]);

      __builtin_amdgcn_s_setprio(1);
      #pragma unroll
      for (int f = 0; f < 4; f++) {
        const int vrow = f * 16 + l15;
        const int vxm = (vrow & 7) << 4;
        bf16x8 v0 = *reinterpret_cast<const bf16x8*>(Vb + vrow * 128 + ((l4 * 16) ^ vxm));
        bf16x8 v1 = *reinterpret_cast<const bf16x8*>(Vb + vrow * 128 + ((64 + l4 * 16) ^ vxm));
        oT[f] = __builtin_amdgcn_mfma_f32_16x16x32_bf16(v0, pb0, oT[f], 0, 0, 0);
        oT[f] = __builtin_amdgcn_mfma_f32_16x16x32_bf16(v1, pb1, oT[f], 0, 0, 0);
      }
      __builtin_amdgcn_s_setprio(0);
    }

    __builtin_amdgcn_s_barrier();   // protect LDS reuse; no drain
    buf ^= 1;
  }

  const float inv = 1.f / l_run;
  #pragma unroll
  for (int f = 0; f < 4; f++) {
    uint2 pk2;
    pk2.x = cvt_pk(oT[f][0] * inv, oT[f][1] * inv);
    pk2.y = cvt_pk(oT[f][2] * inv, oT[f][3] * inv);
    *reinterpret_cast<uint2*>(
        &yb[(size_t)(b * T_ + qrow) * 1024 + h * 64 + f * 16 + l4 * 4]) = pk2;
  }
}

// ---------- launcher ----------
extern "C" void kernel_launch(void* const* d_in, const int* in_sizes, int n_in,
                              void* d_out, int out_size, void* d_ws, size_t ws_size,
                              hipStream_t stream) {
  const float* x         = (const float*)d_in[0];
  const float* cosT      = (const float*)d_in[1];
  const float* sinT      = (const float*)d_in[2];
  const float* W_kv_down = (const float*)d_in[3];
  const float* W_kv_up   = (const float*)d_in[4];
  const float* W_k_rope  = (const float*)d_in[5];
  const float* W_q_down  = (const float*)d_in[6];
  const float* W_q_up    = (const float*)d_in[7];
  const float* W_q_rope  = (const float*)d_in[8];
  const float* W_out     = (const float*)d_in[9];
  float* out = (float*)d_out;
  char* ws = (char*)d_ws;

  u16* xb    = (u16*)(ws + 0);              // 4096x1024 (reused as yb)
  u16* lat   = (u16*)(ws + 8388608);        // 4096x640
  u16* WdT   = (u16*)(ws + 13631488);       // 640x1024
  u16* WkvT  = (u16*)(ws + 14942208);       // 2048x256
  u16* WqT   = (u16*)(ws + 15990784);       // 2048x384
  u16* WoutT = (u16*)(ws + 17563648);       // 1024x1024
  u16* kvo   = (u16*)(ws + 19660800);       // 4096x2048 (kv_up | k_rope)
  u16* qo    = (u16*)(ws + 36438016);       // 4096x2048 (q_up | q_rope)
  u16* VT    = (u16*)(ws + 53215232);       // [2][1024][2048] V^T
  u16* yb    = (u16*)(ws + 0);

  conv_x_kernel<<<4096, 256, 0, stream>>>(x, xb);

  TJobs jobs;
  jobs.j[0] = {W_kv_down, WdT,   1024, 256,  1024, 0,    0};
  jobs.j[1] = {W_q_down,  WdT,   1024, 384,  1024, 256,  256};
  jobs.j[2] = {W_kv_up,   WkvT,  256,  1024, 256,  0,    640};
  jobs.j[3] = {W_k_rope,  WkvT,  256,  1024, 256,  1024, 896};
  jobs.j[4] = {W_q_up,    WqT,   384,  1024, 384,  0,    1152};
  jobs.j[5] = {W_q_rope,  WqT,   384,  1024, 384,  1024, 1536};
  jobs.j[6] = {W_out,     WoutT, 1024, 1024, 1024, 0,    1920};
  transpose_all_kernel<<<2944, dim3(32, 8), 0, stream>>>(jobs);

  gemm_bt<<<dim3(5, 32), 256, 0, stream>>>(xb, 1024, WdT, 1024, lat, 640, 1024, 0,
                                           nullptr, nullptr, nullptr);
  gemm_bt<<<dim3(16, 32), 256, 0, stream>>>(lat, 640, WkvT, 256, kvo, 2048, 256, 2,
                                            VT, cosT, sinT);
  gemm_bt<<<dim3(16, 32), 256, 0, stream>>>(lat + 256, 640, WqT, 384, qo, 2048, 384, 3,
                                            nullptr, cosT, sinT);

  attn_kernel<<<512, 512, 0, stream>>>(qo, kvo, VT, yb);

  gemm_bt<<<dim3(8, 32), 256, 0, stream>>>(yb, 1024, WoutT, 1024, out, 1024, 1024, 1,
                                           nullptr, nullptr, nullptr);
}

// Round 8
// 220.079 us; speedup vs baseline: 1.0588x; 1.0588x over previous
//
#include <hip/hip_runtime.h>
#include <stdint.h>

typedef unsigned short u16;
typedef __bf16 bf16x8 __attribute__((ext_vector_type(8)));
typedef float f32x4 __attribute__((ext_vector_type(4)));

#define B_ 2
#define T_ 2048

// ---------- helpers ----------
__device__ __forceinline__ u16 f2b(float f) {
  unsigned u = __float_as_uint(f);
  u += 0x7fffu + ((u >> 16) & 1u);
  return (u16)(u >> 16);
}
__device__ __forceinline__ float b2f(u16 v) {
  return __uint_as_float(((unsigned)v) << 16);
}
__device__ __forceinline__ unsigned cvt_pk(float lo, float hi) {
  unsigned r;
  asm("v_cvt_pk_bf16_f32 %0, %1, %2" : "=v"(r) : "v"(lo), "v"(hi));
  return r;
}
__device__ __forceinline__ float ex2(float x) {  // 2^x
  float r;
  asm("v_exp_f32 %0, %1" : "=v"(r) : "v"(x));
  return r;
}

using gu32 = __attribute__((address_space(1))) const unsigned int;
using lu32 = __attribute__((address_space(3))) unsigned int;
__device__ __forceinline__ void gl_lds16(const u16* g, u16* l) {
  __builtin_amdgcn_global_load_lds((gu32*)g, (lu32*)l, 16, 0, 0);
}

// ---------- prep: x fp32->bf16 (blocks 0..4095) + weight transposes ----------
struct TJob { const float* src; u16* dst; int K, N, ldt, row_off, blk0; };
struct TJobs { TJob j[7]; };

__global__ __launch_bounds__(256) void prep_kernel(const float* __restrict__ x,
                                                   u16* __restrict__ xb, TJobs jobs) {
  int bid = blockIdx.x;
  int tid = threadIdx.x;
  if (bid < 4096) {
    int i = (bid * 256 + tid) * 4;
    float4 v = *reinterpret_cast<const float4*>(x + i);
    union { u16 h[4]; unsigned long long ll; } pk;
    pk.h[0] = f2b(v.x); pk.h[1] = f2b(v.y); pk.h[2] = f2b(v.z); pk.h[3] = f2b(v.w);
    *reinterpret_cast<unsigned long long*>(xb + i) = pk.ll;
    return;
  }
  bid -= 4096;
  __shared__ float tile[32][33];
  int ji = 0;
  #pragma unroll
  for (int i = 6; i > 0; --i)
    if (bid >= jobs.j[i].blk0) { ji = i; break; }
  const TJob jb = jobs.j[ji];
  int local = bid - jb.blk0;
  int nb = jb.N >> 5;
  int n0 = (local % nb) * 32, k0 = (local / nb) * 32;
  int cx = tid & 31, ry = tid >> 5;
  #pragma unroll
  for (int i = 0; i < 4; i++)
    tile[ry + i * 8][cx] = jb.src[(size_t)(k0 + ry + i * 8) * jb.N + n0 + cx];
  __syncthreads();
  #pragma unroll
  for (int i = 0; i < 4; i++)
    jb.dst[(size_t)(jb.row_off + n0 + ry + i * 8) * jb.ldt + k0 + cx] =
        f2b(tile[cx][ry + i * 8]);
}

// ---------- GEMM: 8 waves, 128x128 tile, single barrier/k-step ----------
// mode: 0 bf16 out; 1 f32 out; 2 kvo (VT copy col<1024, rope col>=1024); 3 qo (rope)
struct GJob { const u16* A; const u16* Bt; void* C; int lda, ldb, ldc, K, mode; };

__global__ __launch_bounds__(512) void gemm_bt8(GJob j0, GJob j1, int split,
                                                u16* __restrict__ vt,
                                                const float* __restrict__ cosT,
                                                const float* __restrict__ sinT) {
  __shared__ u16 As[2][128 * 32];
  __shared__ u16 Bs[2][128 * 32];
  const bool first = (int)blockIdx.x < split;
  const GJob jb = first ? j0 : j1;
  const int bx = blockIdx.x - (first ? 0 : split);
  const int tid = threadIdx.x;
  const int wave = tid >> 6, lane = tid & 63;
  const int wr = wave >> 1, wc = wave & 1;   // wave grid 4(M) x 2(N): 32 x 64 per wave
  const int l15 = lane & 15, l4 = lane >> 4;
  const int m0 = blockIdx.y * 128, n0 = bx * 128;
  const int lr = lane >> 2;
  const int lc = (lane & 3) * 8;

  f32x4 acc[2][4];
  const f32x4 fzero = {0.f, 0.f, 0.f, 0.f};
  #pragma unroll
  for (int m = 0; m < 2; m++)
    #pragma unroll
    for (int n = 0; n < 4; n++)
      acc[m][n] = fzero;

  const u16* gA = jb.A  + (size_t)(m0 + wave * 16 + lr) * jb.lda + lc;
  const u16* gB = jb.Bt + (size_t)(n0 + wave * 16 + lr) * jb.ldb + lc;

  auto stage = [&](int buf, int k0) {
    gl_lds16(gA + k0, &As[buf][(wave * 16) * 32]);
    gl_lds16(gB + k0, &Bs[buf][(wave * 16) * 32]);
  };

  stage(0, 0);
  int buf = 0;
  const int K = jb.K;
  for (int k0 = 0; k0 < K; k0 += 32) {
    asm volatile("s_waitcnt vmcnt(0)" ::: "memory");
    __builtin_amdgcn_s_barrier();
    if (k0 + 32 < K) stage(buf ^ 1, k0 + 32);   // after barrier: prev compute done
    bf16x8 af[2], bfr[4];
    #pragma unroll
    for (int m = 0; m < 2; m++)
      af[m] = *reinterpret_cast<const bf16x8*>(&As[buf][(wr * 32 + m * 16 + l15) * 32 + l4 * 8]);
    #pragma unroll
    for (int n = 0; n < 4; n++)
      bfr[n] = *reinterpret_cast<const bf16x8*>(&Bs[buf][(wc * 64 + n * 16 + l15) * 32 + l4 * 8]);
    #pragma unroll
    for (int m = 0; m < 2; m++)
      #pragma unroll
      for (int n = 0; n < 4; n++)
        acc[m][n] = __builtin_amdgcn_mfma_f32_16x16x32_bf16(af[m], bfr[n], acc[m][n], 0, 0, 0);
    buf ^= 1;
  }

  const int row_base = m0 + wr * 32 + l4 * 4;
  const int col_base = n0 + wc * 64 + l15;
  const int mode = jb.mode;
  const int ldc = jb.ldc;

  if (mode == 1) {
    float* Cf = (float*)jb.C;
    #pragma unroll
    for (int m = 0; m < 2; m++)
      #pragma unroll
      for (int n = 0; n < 4; n++)
        #pragma unroll
        for (int r = 0; r < 4; r++)
          Cf[(size_t)(row_base + m * 16 + r) * ldc + col_base + n * 16] = acc[m][n][r];
    return;
  }

  // fused rope on the rope half (cols >= 1024), f32 before quantization.
  if (mode >= 2 && (n0 + wc * 64) >= 1024) {
    #pragma unroll
    for (int m = 0; m < 2; m++)
      #pragma unroll
      for (int r = 0; r < 4; r++) {
        int t = (row_base + m * 16 + r) & (T_ - 1);
        const float* cp = cosT + t * 64 + l15;
        const float* sp = sinT + t * 64 + l15;
        float c0 = cp[0], c16 = cp[16], c32 = cp[32], c48 = cp[48];
        float s0 = sp[0], s16 = sp[16], s32 = sp[32], s48 = sp[48];
        float x0 = acc[m][0][r], x1 = acc[m][1][r];
        float x2 = acc[m][2][r], x3 = acc[m][3][r];
        acc[m][0][r] = x0 * c0 - x2 * s0;
        acc[m][1][r] = x1 * c16 - x3 * s16;
        acc[m][2][r] = x2 * c32 + x0 * s32;
        acc[m][3][r] = x3 * c48 + x1 * s48;
      }
  }

  u16* Cb = (u16*)jb.C;
  #pragma unroll
  for (int m = 0; m < 2; m++)
    #pragma unroll
    for (int n = 0; n < 4; n++)
      #pragma unroll
      for (int r = 0; r < 4; r++)
        Cb[(size_t)(row_base + m * 16 + r) * ldc + col_base + n * 16] = f2b(acc[m][n][r]);

  if (mode == 2) {
    // transposed copy of V content cols: VT[(b*1024+col)][t]
    #pragma unroll
    for (int m = 0; m < 2; m++)
      #pragma unroll
      for (int n = 0; n < 4; n++) {
        int col = col_base + n * 16;
        if (col < 1024) {
          int mm = row_base + m * 16;
          int bb = mm >> 11, tt = mm & 2047;
          uint2 pk2;
          pk2.x = cvt_pk(acc[m][n][0], acc[m][n][1]);
          pk2.y = cvt_pk(acc[m][n][2], acc[m][n][3]);
          *reinterpret_cast<uint2*>(&vt[(size_t)(bb * 1024 + col) * 2048 + tt]) = pk2;
        }
      }
  }
}

// ---------- causal flash attention: QBLK=128, 8 waves, single barrier/tile ----------
__global__ __launch_bounds__(512) void attn_kernel(const u16* __restrict__ qo,
                                                   const u16* __restrict__ kvo,
                                                   const u16* __restrict__ vtg,
                                                   u16* __restrict__ yb) {
  __shared__ u16 K_lds[2][64 * 128];   // rows swizzled: byte ^= (row&7)<<4
  __shared__ u16 V_lds[2][64 * 64];    // V^T, same swizzle
  __shared__ u16 P_lds[8][16][72];
  const int tid = threadIdx.x;
  const int wave = tid >> 6, lane = tid & 63;
  const int l15 = lane & 15, l4 = lane >> 4;
  const int bid = blockIdx.x;
  const int bh = bid & 31;
  const int qi = 15 - (bid >> 5);      // LPT: heaviest first
  const int b = bh >> 4, h = bh & 15;
  const int q0 = qi * 128;
  const int qrow = q0 + wave * 16 + l15;

  const u16* qb = qo + (size_t)(b * T_ + qrow) * 2048 + h * 64;
  bf16x8 qf[4];
  qf[0] = *reinterpret_cast<const bf16x8*>(qb + l4 * 8);
  qf[1] = *reinterpret_cast<const bf16x8*>(qb + 32 + l4 * 8);
  qf[2] = *reinterpret_cast<const bf16x8*>(qb + 1024 + l4 * 8);
  qf[3] = *reinterpret_cast<const bf16x8*>(qb + 1056 + l4 * 8);

  const u16* Kbase = kvo + (size_t)(b * T_) * 2048 + h * 64;
  const u16* Vbase = vtg + (size_t)(b * 1024 + h * 64) * 2048;

  const int krow_i = lane >> 4;
  const int kc2 = (lane & 15) * 16;
  const int vrow_i = lane >> 3;
  const int vc2 = (lane & 7) * 16;

  auto stage = [&](int buf, int kv0) {
    #pragma unroll
    for (int j = 0; j < 2; j++) {
      int row = wave * 8 + j * 4 + krow_i;
      int c2x = kc2 ^ ((row & 7) << 4);
      int cu = c2x >> 1;
      const u16* src = Kbase + (size_t)(kv0 + row) * 2048 + (cu < 64 ? cu : 960 + cu);
      gl_lds16(src, &K_lds[buf][(wave * 8 + j * 4) * 128]);
    }
    {
      int row = wave * 8 + vrow_i;
      int c2x = vc2 ^ ((row & 7) << 4);
      const u16* src = Vbase + (size_t)row * 2048 + kv0 + (c2x >> 1);
      gl_lds16(src, &V_lds[buf][(wave * 8) * 64]);
    }
  };

  const f32x4 fzero = {0.f, 0.f, 0.f, 0.f};
  f32x4 oT[4];
  #pragma unroll
  for (int f = 0; f < 4; f++) oT[f] = fzero;
  float m_run = -1e30f, l_run = 0.f;

  const float SCALE2 = 0.125f * 1.44269504f;   // 1/sqrt(64) * log2(e)
  const int nt = qi * 2 + 2;
  const int t_diag = qi * 2 + (wave >> 2);

  stage(0, 0);
  int buf = 0;

  for (int t = 0; t < nt; t++) {
    const int kv0 = t * 64;
    // drain own previous stage (had a full tile to land), sync, then issue next
    asm volatile("s_waitcnt vmcnt(0)" ::: "memory");
    __builtin_amdgcn_s_barrier();
    if (t + 1 < nt) stage(buf ^ 1, kv0 + 64);

    if (t <= t_diag) {
      const char* Kb = (const char*)&K_lds[buf][0];
      const char* Vb = (const char*)&V_lds[buf][0];

      f32x4 sT[4];
      #pragma unroll
      for (int c = 0; c < 4; c++) sT[c] = fzero;
      #pragma unroll
      for (int c = 0; c < 4; c++) {
        const int krow = c * 16 + l15;
        const int kxm = (krow & 7) << 4;
        #pragma unroll
        for (int s = 0; s < 4; s++) {
          bf16x8 kf = *reinterpret_cast<const bf16x8*>(
              Kb + krow * 256 + ((s * 64 + l4 * 16) ^ kxm));
          sT[c] = __builtin_amdgcn_mfma_f32_16x16x32_bf16(kf, qf[s], sT[c], 0, 0, 0);
        }
      }

      const bool diag = (t == t_diag);
      float p[4][4];
      float mx = -1e30f;
      #pragma unroll
      for (int c = 0; c < 4; c++)
        #pragma unroll
        for (int r = 0; r < 4; r++) {
          float s = sT[c][r] * SCALE2;
          if (diag) {
            int kv = kv0 + c * 16 + l4 * 4 + r;
            if (kv > qrow) s = -1e30f;
          }
          p[c][r] = s;
          mx = fmaxf(mx, s);
        }
      mx = fmaxf(mx, __shfl_xor(mx, 16));
      mx = fmaxf(mx, __shfl_xor(mx, 32));
      if (__any(mx > m_run + 11.5f)) {         // defer-max (T13)
        float m_new = fmaxf(m_run, mx);
        float corr = ex2(m_run - m_new);
        l_run *= corr;
        #pragma unroll
        for (int f = 0; f < 4; f++) oT[f] *= corr;
        m_run = m_new;
      }
      float rsum = 0.f;
      #pragma unroll
      for (int c = 0; c < 4; c++)
        #pragma unroll
        for (int r = 0; r < 4; r++) {
          float pe = ex2(p[c][r] - m_run);
          p[c][r] = pe;
          rsum += pe;
        }
      rsum += __shfl_xor(rsum, 16);
      rsum += __shfl_xor(rsum, 32);
      l_run += rsum;

      #pragma unroll
      for (int c = 0; c < 4; c++) {
        uint2 pk2;
        pk2.x = cvt_pk(p[c][0], p[c][1]);
        pk2.y = cvt_pk(p[c][2], p[c][3]);
        *reinterpret_cast<uint2*>(&P_lds[wave][l15][c * 16 + l4 * 4]) = pk2;
      }
      bf16x8 pb0 = *reinterpret_cast<const bf16x8*>(&P_lds[wave][l15][l4 * 8]);
      bf16x8 pb1 = *reinterpret_cast<const bf16x8*>(&P_lds[wave][l15][32 + l4 * 8]);

      #pragma unroll
      for (int f = 0; f < 4; f++) {
        const int vrow = f * 16 + l15;
        const int vxm = (vrow & 7) << 4;
        bf16x8 v0 = *reinterpret_cast<const bf16x8*>(Vb + vrow * 128 + ((l4 * 16) ^ vxm));
        bf16x8 v1 = *reinterpret_cast<const bf16x8*>(Vb + vrow * 128 + ((64 + l4 * 16) ^ vxm));
        oT[f] = __builtin_amdgcn_mfma_f32_16x16x32_bf16(v0, pb0, oT[f], 0, 0, 0);
        oT[f] = __builtin_amdgcn_mfma_f32_16x16x32_bf16(v1, pb1, oT[f], 0, 0, 0);
      }
    }

    buf ^= 1;
  }

  const float inv = 1.f / l_run;
  #pragma unroll
  for (int f = 0; f < 4; f++) {
    uint2 pk2;
    pk2.x = cvt_pk(oT[f][0] * inv, oT[f][1] * inv);
    pk2.y = cvt_pk(oT[f][2] * inv, oT[f][3] * inv);
    *reinterpret_cast<uint2*>(
        &yb[(size_t)(b * T_ + qrow) * 1024 + h * 64 + f * 16 + l4 * 4]) = pk2;
  }
}

// ---------- launcher ----------
extern "C" void kernel_launch(void* const* d_in, const int* in_sizes, int n_in,
                              void* d_out, int out_size, void* d_ws, size_t ws_size,
                              hipStream_t stream) {
  const float* x         = (const float*)d_in[0];
  const float* cosT      = (const float*)d_in[1];
  const float* sinT      = (const float*)d_in[2];
  const float* W_kv_down = (const float*)d_in[3];
  const float* W_kv_up   = (const float*)d_in[4];
  const float* W_k_rope  = (const float*)d_in[5];
  const float* W_q_down  = (const float*)d_in[6];
  const float* W_q_up    = (const float*)d_in[7];
  const float* W_q_rope  = (const float*)d_in[8];
  const float* W_out     = (const float*)d_in[9];
  float* out = (float*)d_out;
  char* ws = (char*)d_ws;

  u16* xb    = (u16*)(ws + 0);              // 4096x1024 (reused as yb)
  u16* lat   = (u16*)(ws + 8388608);        // 4096x640
  u16* WdT   = (u16*)(ws + 13631488);       // 640x1024
  u16* WkvT  = (u16*)(ws + 14942208);       // 2048x256
  u16* WqT   = (u16*)(ws + 15990784);       // 2048x384
  u16* WoutT = (u16*)(ws + 17563648);       // 1024x1024
  u16* kvo   = (u16*)(ws + 19660800);       // 4096x2048 (kv_up | k_rope)
  u16* qo    = (u16*)(ws + 36438016);       // 4096x2048 (q_up | q_rope)
  u16* VT    = (u16*)(ws + 53215232);       // [2][1024][2048] V^T
  u16* yb    = (u16*)(ws + 0);

  TJobs jobs;
  jobs.j[0] = {W_kv_down, WdT,   1024, 256,  1024, 0,    0};
  jobs.j[1] = {W_q_down,  WdT,   1024, 384,  1024, 256,  256};
  jobs.j[2] = {W_kv_up,   WkvT,  256,  1024, 256,  0,    640};
  jobs.j[3] = {W_k_rope,  WkvT,  256,  1024, 256,  1024, 896};
  jobs.j[4] = {W_q_up,    WqT,   384,  1024, 384,  0,    1152};
  jobs.j[5] = {W_q_rope,  WqT,   384,  1024, 384,  1024, 1536};
  jobs.j[6] = {W_out,     WoutT, 1024, 1024, 1024, 0,    1920};
  prep_kernel<<<7040, 256, 0, stream>>>(x, xb, jobs);

  // gemm1: lat = xb @ [W_kv_down | W_q_down]
  GJob g1 = {xb, WdT, lat, 1024, 1024, 640, 1024, 0};
  gemm_bt8<<<dim3(5, 32), 512, 0, stream>>>(g1, g1, 5, nullptr, nullptr, nullptr);

  // gemm2+3 fused: kvo = lat[:,:256]@[W_kv_up|W_k_rope] ; qo = lat[:,256:]@[W_q_up|W_q_rope]
  GJob g2 = {lat,       WkvT, kvo, 640, 256, 2048, 256, 2};
  GJob g3 = {lat + 256, WqT,  qo,  640, 384, 2048, 384, 3};
  gemm_bt8<<<dim3(32, 32), 512, 0, stream>>>(g2, g3, 16, VT, cosT, sinT);

  attn_kernel<<<512, 512, 0, stream>>>(qo, kvo, VT, yb);

  // gemm4: out = yb @ W_out (fp32)
  GJob g4 = {yb, WoutT, out, 1024, 1024, 1024, 1024, 1};
  gemm_bt8<<<dim3(8, 32), 512, 0, stream>>>(g4, g4, 8, nullptr, nullptr, nullptr);
}

// Round 9
// 215.749 us; speedup vs baseline: 1.0800x; 1.0201x over previous
//
#include <hip/hip_runtime.h>
#include <stdint.h>

typedef unsigned short u16;
typedef __bf16 bf16x8 __attribute__((ext_vector_type(8)));
typedef float f32x4 __attribute__((ext_vector_type(4)));

#define B_ 2
#define T_ 2048

// ---------- helpers ----------
__device__ __forceinline__ u16 f2b(float f) {
  unsigned u = __float_as_uint(f);
  u += 0x7fffu + ((u >> 16) & 1u);
  return (u16)(u >> 16);
}
__device__ __forceinline__ unsigned cvt_pk(float lo, float hi) {
  unsigned r;
  asm("v_cvt_pk_bf16_f32 %0, %1, %2" : "=v"(r) : "v"(lo), "v"(hi));
  return r;
}
__device__ __forceinline__ float ex2(float x) {  // 2^x
  float r;
  asm("v_exp_f32 %0, %1" : "=v"(r) : "v"(x));
  return r;
}

using gu32 = __attribute__((address_space(1))) const unsigned int;
using lu32 = __attribute__((address_space(3))) unsigned int;
__device__ __forceinline__ void gl_lds16(const u16* g, u16* l) {
  __builtin_amdgcn_global_load_lds((gu32*)g, (lu32*)l, 16, 0, 0);
}

// ---------- prep: x fp32->bf16 (blocks 0..4095) + weight transposes ----------
struct TJob { const float* src; u16* dst; int K, N, ldt, row_off, blk0; };
struct TJobs { TJob j[7]; };

__global__ __launch_bounds__(256) void prep_kernel(const float* __restrict__ x,
                                                   u16* __restrict__ xb, TJobs jobs) {
  int bid = blockIdx.x;
  int tid = threadIdx.x;
  if (bid < 4096) {
    int i = (bid * 256 + tid) * 4;
    float4 v = *reinterpret_cast<const float4*>(x + i);
    union { u16 h[4]; unsigned long long ll; } pk;
    pk.h[0] = f2b(v.x); pk.h[1] = f2b(v.y); pk.h[2] = f2b(v.z); pk.h[3] = f2b(v.w);
    *reinterpret_cast<unsigned long long*>(xb + i) = pk.ll;
    return;
  }
  bid -= 4096;
  __shared__ float tile[32][33];
  int ji = 0;
  #pragma unroll
  for (int i = 6; i > 0; --i)
    if (bid >= jobs.j[i].blk0) { ji = i; break; }
  const TJob jb = jobs.j[ji];
  int local = bid - jb.blk0;
  int nb = jb.N >> 5;
  int n0 = (local % nb) * 32, k0 = (local / nb) * 32;
  int cx = tid & 31, ry = tid >> 5;
  #pragma unroll
  for (int i = 0; i < 4; i++)
    tile[ry + i * 8][cx] = jb.src[(size_t)(k0 + ry + i * 8) * jb.N + n0 + cx];
  __syncthreads();
  #pragma unroll
  for (int i = 0; i < 4; i++)
    jb.dst[(size_t)(jb.row_off + n0 + ry + i * 8) * jb.ldt + k0 + cx] =
        f2b(tile[cx][ry + i * 8]);
}

// ---------- GEMM: 8 waves, 128x128 tile, BK=64, swizzled LDS ----------
// mode: 0 bf16 out; 1 f32 out; 2/3 rope on cols>=1024 then bf16 out
struct GJob { const u16* A; const u16* Bt; void* C; int lda, ldb, ldc, K, mode; };

__global__ __launch_bounds__(512) void gemm_bt8(GJob j0, GJob j1, int split,
                                                const float* __restrict__ cosT,
                                                const float* __restrict__ sinT) {
  __shared__ u16 As[2][128 * 64];
  __shared__ u16 Bs[2][128 * 64];
  const bool first = (int)blockIdx.x < split;
  const GJob jb = first ? j0 : j1;
  const int bx = blockIdx.x - (first ? 0 : split);
  const int tid = threadIdx.x;
  const int wave = tid >> 6, lane = tid & 63;
  const int wr = wave >> 1, wc = wave & 1;   // wave grid 4(M) x 2(N): 32 x 64 / wave
  const int l15 = lane & 15, l4 = lane >> 4;
  const int m0 = blockIdx.y * 128, n0 = bx * 128;
  // stage: lane covers LDS row (wave*16 + chunk*8 + (lane>>3)), 8 u16 at
  // physical col (lane&7)*8; logical col is XOR-swizzled by row&7 = lane>>3.
  const int srow = lane >> 3;
  const int scol = ((lane & 7) ^ srow) * 8;

  f32x4 acc[2][4];
  const f32x4 fzero = {0.f, 0.f, 0.f, 0.f};
  #pragma unroll
  for (int m = 0; m < 2; m++)
    #pragma unroll
    for (int n = 0; n < 4; n++)
      acc[m][n] = fzero;

  const u16* gA = jb.A  + (size_t)(m0 + wave * 16 + srow) * jb.lda + scol;
  const u16* gB = jb.Bt + (size_t)(n0 + wave * 16 + srow) * jb.ldb + scol;

  auto stage = [&](int buf, int k0) {
    gl_lds16(gA + k0,                      &As[buf][(wave * 16) * 64]);
    gl_lds16(gA + (size_t)8 * jb.lda + k0, &As[buf][(wave * 16 + 8) * 64]);
    gl_lds16(gB + k0,                      &Bs[buf][(wave * 16) * 64]);
    gl_lds16(gB + (size_t)8 * jb.ldb + k0, &Bs[buf][(wave * 16 + 8) * 64]);
  };

  stage(0, 0);
  int buf = 0;
  const int K = jb.K;
  for (int k0 = 0; k0 < K; k0 += 64) {
    asm volatile("s_waitcnt vmcnt(0)" ::: "memory");
    __builtin_amdgcn_s_barrier();
    if (k0 + 64 < K) stage(buf ^ 1, k0 + 64);
    bf16x8 af[2][2], bfr[4][2];
    #pragma unroll
    for (int m = 0; m < 2; m++) {
      const int row = wr * 32 + m * 16 + l15;
      const int xm = (row & 7) * 8;
      af[m][0] = *reinterpret_cast<const bf16x8*>(&As[buf][row * 64 + ((l4 * 8) ^ xm)]);
      af[m][1] = *reinterpret_cast<const bf16x8*>(&As[buf][row * 64 + ((32 + l4 * 8) ^ xm)]);
    }
    #pragma unroll
    for (int n = 0; n < 4; n++) {
      const int row = wc * 64 + n * 16 + l15;
      const int xm = (row & 7) * 8;
      bfr[n][0] = *reinterpret_cast<const bf16x8*>(&Bs[buf][row * 64 + ((l4 * 8) ^ xm)]);
      bfr[n][1] = *reinterpret_cast<const bf16x8*>(&Bs[buf][row * 64 + ((32 + l4 * 8) ^ xm)]);
    }
    #pragma unroll
    for (int m = 0; m < 2; m++)
      #pragma unroll
      for (int n = 0; n < 4; n++) {
        acc[m][n] = __builtin_amdgcn_mfma_f32_16x16x32_bf16(af[m][0], bfr[n][0], acc[m][n], 0, 0, 0);
        acc[m][n] = __builtin_amdgcn_mfma_f32_16x16x32_bf16(af[m][1], bfr[n][1], acc[m][n], 0, 0, 0);
      }
    buf ^= 1;
  }

  const int row_base = m0 + wr * 32 + l4 * 4;
  const int col_base = n0 + wc * 64 + l15;
  const int mode = jb.mode;
  const int ldc = jb.ldc;

  if (mode == 1) {
    float* Cf = (float*)jb.C;
    #pragma unroll
    for (int m = 0; m < 2; m++)
      #pragma unroll
      for (int n = 0; n < 4; n++)
        #pragma unroll
        for (int r = 0; r < 4; r++)
          Cf[(size_t)(row_base + m * 16 + r) * ldc + col_base + n * 16] = acc[m][n][r];
    return;
  }

  // fused rope on the rope half (cols >= 1024), f32 before quantization.
  if (mode >= 2 && (n0 + wc * 64) >= 1024) {
    #pragma unroll
    for (int m = 0; m < 2; m++)
      #pragma unroll
      for (int r = 0; r < 4; r++) {
        int t = (row_base + m * 16 + r) & (T_ - 1);
        const float* cp = cosT + t * 64 + l15;
        const float* sp = sinT + t * 64 + l15;
        float c0 = cp[0], c16 = cp[16], c32 = cp[32], c48 = cp[48];
        float s0 = sp[0], s16 = sp[16], s32 = sp[32], s48 = sp[48];
        float x0 = acc[m][0][r], x1 = acc[m][1][r];
        float x2 = acc[m][2][r], x3 = acc[m][3][r];
        acc[m][0][r] = x0 * c0 - x2 * s0;
        acc[m][1][r] = x1 * c16 - x3 * s16;
        acc[m][2][r] = x2 * c32 + x0 * s32;
        acc[m][3][r] = x3 * c48 + x1 * s48;
      }
  }

  u16* Cb = (u16*)jb.C;
  #pragma unroll
  for (int m = 0; m < 2; m++)
    #pragma unroll
    for (int n = 0; n < 4; n++)
      #pragma unroll
      for (int r = 0; r < 4; r++)
        Cb[(size_t)(row_base + m * 16 + r) * ldc + col_base + n * 16] = f2b(acc[m][n][r]);
}

// ---------- VT transpose: kvo V-cols [4096][0..1024) -> VT[b][col][t] ----------
__global__ __launch_bounds__(256) void vtrans_kernel(const u16* __restrict__ kvo,
                                                     u16* __restrict__ vt) {
  __shared__ u16 tile[64][72];   // 144B rows: 16B-aligned, rows spread 4 banks
  const int tid = threadIdx.x;
  const int cb = blockIdx.x * 64;          // col base (0..960)
  const int rb = blockIdx.y * 64;          // row base (0..4032)
  const int b = rb >> 11, t0 = rb & 2047;
  const int rr = tid >> 3;                 // 0..31
  const int c8 = (tid & 7) * 8;
  #pragma unroll
  for (int i = 0; i < 2; i++) {
    int r = i * 32 + rr;
    uint4 v = *reinterpret_cast<const uint4*>(kvo + (size_t)(rb + r) * 2048 + cb + c8);
    *reinterpret_cast<uint4*>(&tile[r][c8]) = v;
  }
  __syncthreads();
  #pragma unroll
  for (int i = 0; i < 2; i++) {
    int c = i * 32 + rr;                   // output col within tile
    int r8 = c8;                           // 8 consecutive t values
    union { u16 h[8]; uint4 v; } pk;
    #pragma unroll
    for (int j = 0; j < 8; j++) pk.h[j] = tile[r8 + j][c];
    *reinterpret_cast<uint4*>(&vt[(size_t)(b * 1024 + cb + c) * 2048 + t0 + r8]) = pk.v;
  }
}

// ---------- causal flash attention: QBLK=128, 8 waves (unchanged from r8) ----------
__global__ __launch_bounds__(512) void attn_kernel(const u16* __restrict__ qo,
                                                   const u16* __restrict__ kvo,
                                                   const u16* __restrict__ vtg,
                                                   u16* __restrict__ yb) {
  __shared__ u16 K_lds[2][64 * 128];   // rows swizzled: byte ^= (row&7)<<4
  __shared__ u16 V_lds[2][64 * 64];    // V^T, same swizzle
  __shared__ u16 P_lds[8][16][72];
  const int tid = threadIdx.x;
  const int wave = tid >> 6, lane = tid & 63;
  const int l15 = lane & 15, l4 = lane >> 4;
  const int bid = blockIdx.x;
  const int bh = bid & 31;
  const int qi = 15 - (bid >> 5);      // LPT: heaviest first
  const int b = bh >> 4, h = bh & 15;
  const int q0 = qi * 128;
  const int qrow = q0 + wave * 16 + l15;

  const u16* qb = qo + (size_t)(b * T_ + qrow) * 2048 + h * 64;
  bf16x8 qf[4];
  qf[0] = *reinterpret_cast<const bf16x8*>(qb + l4 * 8);
  qf[1] = *reinterpret_cast<const bf16x8*>(qb + 32 + l4 * 8);
  qf[2] = *reinterpret_cast<const bf16x8*>(qb + 1024 + l4 * 8);
  qf[3] = *reinterpret_cast<const bf16x8*>(qb + 1056 + l4 * 8);

  const u16* Kbase = kvo + (size_t)(b * T_) * 2048 + h * 64;
  const u16* Vbase = vtg + (size_t)(b * 1024 + h * 64) * 2048;

  const int krow_i = lane >> 4;
  const int kc2 = (lane & 15) * 16;
  const int vrow_i = lane >> 3;
  const int vc2 = (lane & 7) * 16;

  auto stage = [&](int buf, int kv0) {
    #pragma unroll
    for (int j = 0; j < 2; j++) {
      int row = wave * 8 + j * 4 + krow_i;
      int c2x = kc2 ^ ((row & 7) << 4);
      int cu = c2x >> 1;
      const u16* src = Kbase + (size_t)(kv0 + row) * 2048 + (cu < 64 ? cu : 960 + cu);
      gl_lds16(src, &K_lds[buf][(wave * 8 + j * 4) * 128]);
    }
    {
      int row = wave * 8 + vrow_i;
      int c2x = vc2 ^ ((row & 7) << 4);
      const u16* src = Vbase + (size_t)row * 2048 + kv0 + (c2x >> 1);
      gl_lds16(src, &V_lds[buf][(wave * 8) * 64]);
    }
  };

  const f32x4 fzero = {0.f, 0.f, 0.f, 0.f};
  f32x4 oT[4];
  #pragma unroll
  for (int f = 0; f < 4; f++) oT[f] = fzero;
  float m_run = -1e30f, l_run = 0.f;

  const float SCALE2 = 0.125f * 1.44269504f;   // 1/sqrt(64) * log2(e)
  const int nt = qi * 2 + 2;
  const int t_diag = qi * 2 + (wave >> 2);

  stage(0, 0);
  int buf = 0;

  for (int t = 0; t < nt; t++) {
    const int kv0 = t * 64;
    asm volatile("s_waitcnt vmcnt(0)" ::: "memory");
    __builtin_amdgcn_s_barrier();
    if (t + 1 < nt) stage(buf ^ 1, kv0 + 64);

    if (t <= t_diag) {
      const char* Kb = (const char*)&K_lds[buf][0];
      const char* Vb = (const char*)&V_lds[buf][0];

      f32x4 sT[4];
      #pragma unroll
      for (int c = 0; c < 4; c++) sT[c] = fzero;
      #pragma unroll
      for (int c = 0; c < 4; c++) {
        const int krow = c * 16 + l15;
        const int kxm = (krow & 7) << 4;
        #pragma unroll
        for (int s = 0; s < 4; s++) {
          bf16x8 kf = *reinterpret_cast<const bf16x8*>(
              Kb + krow * 256 + ((s * 64 + l4 * 16) ^ kxm));
          sT[c] = __builtin_amdgcn_mfma_f32_16x16x32_bf16(kf, qf[s], sT[c], 0, 0, 0);
        }
      }

      const bool diag = (t == t_diag);
      float p[4][4];
      float mx = -1e30f;
      #pragma unroll
      for (int c = 0; c < 4; c++)
        #pragma unroll
        for (int r = 0; r < 4; r++) {
          float s = sT[c][r] * SCALE2;
          if (diag) {
            int kv = kv0 + c * 16 + l4 * 4 + r;
            if (kv > qrow) s = -1e30f;
          }
          p[c][r] = s;
          mx = fmaxf(mx, s);
        }
      mx = fmaxf(mx, __shfl_xor(mx, 16));
      mx = fmaxf(mx, __shfl_xor(mx, 32));
      if (__any(mx > m_run + 11.5f)) {         // defer-max (T13)
        float m_new = fmaxf(m_run, mx);
        float corr = ex2(m_run - m_new);
        l_run *= corr;
        #pragma unroll
        for (int f = 0; f < 4; f++) oT[f] *= corr;
        m_run = m_new;
      }
      float rsum = 0.f;
      #pragma unroll
      for (int c = 0; c < 4; c++)
        #pragma unroll
        for (int r = 0; r < 4; r++) {
          float pe = ex2(p[c][r] - m_run);
          p[c][r] = pe;
          rsum += pe;
        }
      rsum += __shfl_xor(rsum, 16);
      rsum += __shfl_xor(rsum, 32);
      l_run += rsum;

      #pragma unroll
      for (int c = 0; c < 4; c++) {
        uint2 pk2;
        pk2.x = cvt_pk(p[c][0], p[c][1]);
        pk2.y = cvt_pk(p[c][2], p[c][3]);
        *reinterpret_cast<uint2*>(&P_lds[wave][l15][c * 16 + l4 * 4]) = pk2;
      }
      bf16x8 pb0 = *reinterpret_cast<const bf16x8*>(&P_lds[wave][l15][l4 * 8]);
      bf16x8 pb1 = *reinterpret_cast<const bf16x8*>(&P_lds[wave][l15][32 + l4 * 8]);

      #pragma unroll
      for (int f = 0; f < 4; f++) {
        const int vrow = f * 16 + l15;
        const int vxm = (vrow & 7) << 4;
        bf16x8 v0 = *reinterpret_cast<const bf16x8*>(Vb + vrow * 128 + ((l4 * 16) ^ vxm));
        bf16x8 v1 = *reinterpret_cast<const bf16x8*>(Vb + vrow * 128 + ((64 + l4 * 16) ^ vxm));
        oT[f] = __builtin_amdgcn_mfma_f32_16x16x32_bf16(v0, pb0, oT[f], 0, 0, 0);
        oT[f] = __builtin_amdgcn_mfma_f32_16x16x32_bf16(v1, pb1, oT[f], 0, 0, 0);
      }
    }

    buf ^= 1;
  }

  const float inv = 1.f / l_run;
  #pragma unroll
  for (int f = 0; f < 4; f++) {
    uint2 pk2;
    pk2.x = cvt_pk(oT[f][0] * inv, oT[f][1] * inv);
    pk2.y = cvt_pk(oT[f][2] * inv, oT[f][3] * inv);
    *reinterpret_cast<uint2*>(
        &yb[(size_t)(b * T_ + qrow) * 1024 + h * 64 + f * 16 + l4 * 4]) = pk2;
  }
}

// ---------- launcher ----------
extern "C" void kernel_launch(void* const* d_in, const int* in_sizes, int n_in,
                              void* d_out, int out_size, void* d_ws, size_t ws_size,
                              hipStream_t stream) {
  const float* x         = (const float*)d_in[0];
  const float* cosT      = (const float*)d_in[1];
  const float* sinT      = (const float*)d_in[2];
  const float* W_kv_down = (const float*)d_in[3];
  const float* W_kv_up   = (const float*)d_in[4];
  const float* W_k_rope  = (const float*)d_in[5];
  const float* W_q_down  = (const float*)d_in[6];
  const float* W_q_up    = (const float*)d_in[7];
  const float* W_q_rope  = (const float*)d_in[8];
  const float* W_out     = (const float*)d_in[9];
  float* out = (float*)d_out;
  char* ws = (char*)d_ws;

  u16* xb    = (u16*)(ws + 0);              // 4096x1024 (reused as yb)
  u16* lat   = (u16*)(ws + 8388608);        // 4096x640
  u16* WdT   = (u16*)(ws + 13631488);       // 640x1024
  u16* WkvT  = (u16*)(ws + 14942208);       // 2048x256
  u16* WqT   = (u16*)(ws + 15990784);       // 2048x384
  u16* WoutT = (u16*)(ws + 17563648);       // 1024x1024
  u16* kvo   = (u16*)(ws + 19660800);       // 4096x2048 (kv_up | k_rope)
  u16* qo    = (u16*)(ws + 36438016);       // 4096x2048 (q_up | q_rope)
  u16* VT    = (u16*)(ws + 53215232);       // [2][1024][2048] V^T
  u16* yb    = (u16*)(ws + 0);

  TJobs jobs;
  jobs.j[0] = {W_kv_down, WdT,   1024, 256,  1024, 0,    0};
  jobs.j[1] = {W_q_down,  WdT,   1024, 384,  1024, 256,  256};
  jobs.j[2] = {W_kv_up,   WkvT,  256,  1024, 256,  0,    640};
  jobs.j[3] = {W_k_rope,  WkvT,  256,  1024, 256,  1024, 896};
  jobs.j[4] = {W_q_up,    WqT,   384,  1024, 384,  0,    1152};
  jobs.j[5] = {W_q_rope,  WqT,   384,  1024, 384,  1024, 1536};
  jobs.j[6] = {W_out,     WoutT, 1024, 1024, 1024, 0,    1920};
  prep_kernel<<<7040, 256, 0, stream>>>(x, xb, jobs);

  // gemm1: lat = xb @ [W_kv_down | W_q_down]
  GJob g1 = {xb, WdT, lat, 1024, 1024, 640, 1024, 0};
  gemm_bt8<<<dim3(5, 32), 512, 0, stream>>>(g1, g1, 5, nullptr, nullptr);

  // gemm2+3 fused: kvo = lat[:,:256]@[W_kv_up|W_k_rope] ; qo = lat[:,256:]@[W_q_up|W_q_rope]
  GJob g2 = {lat,       WkvT, kvo, 640, 256, 2048, 256, 2};
  GJob g3 = {lat + 256, WqT,  qo,  640, 384, 2048, 384, 3};
  gemm_bt8<<<dim3(32, 32), 512, 0, stream>>>(g2, g3, 16, cosT, sinT);

  // VT = transpose of kvo's V-content columns (coalesced)
  vtrans_kernel<<<dim3(16, 64), 256, 0, stream>>>(kvo, VT);

  attn_kernel<<<512, 512, 0, stream>>>(qo, kvo, VT, yb);

  // gemm4: out = yb @ W_out (fp32)
  GJob g4 = {yb, WoutT, out, 1024, 1024, 1024, 1024, 1};
  gemm_bt8<<<dim3(8, 32), 512, 0, stream>>>(g4, g4, 8, nullptr, nullptr);
}

// Round 10
// 213.813 us; speedup vs baseline: 1.0898x; 1.0091x over previous
//
#include <hip/hip_runtime.h>
#include <stdint.h>

typedef unsigned short u16;
typedef __bf16 bf16x8 __attribute__((ext_vector_type(8)));
typedef float f32x4 __attribute__((ext_vector_type(4)));

#define B_ 2
#define T_ 2048

// ---------- helpers ----------
__device__ __forceinline__ u16 f2b(float f) {
  unsigned u = __float_as_uint(f);
  u += 0x7fffu + ((u >> 16) & 1u);
  return (u16)(u >> 16);
}
__device__ __forceinline__ unsigned cvt_pk(float lo, float hi) {
  unsigned r;
  asm("v_cvt_pk_bf16_f32 %0, %1, %2" : "=v"(r) : "v"(lo), "v"(hi));
  return r;
}
__device__ __forceinline__ float ex2(float x) {  // 2^x
  float r;
  asm("v_exp_f32 %0, %1" : "=v"(r) : "v"(x));
  return r;
}
// PV mfma: D = A(V^T frag, 4 bf16) x B(P^T frag, 4 bf16) + D, 16x16x16
__device__ __forceinline__ void mfma16(f32x4& acc, uint2 a, uint2 b) {
  asm volatile("v_mfma_f32_16x16x16_bf16 %0, %1, %2, %0"
               : "+v"(acc) : "v"(a), "v"(b));
}

using gu32 = __attribute__((address_space(1))) const unsigned int;
using lu32 = __attribute__((address_space(3))) unsigned int;
__device__ __forceinline__ void gl_lds16(const u16* g, u16* l) {
  __builtin_amdgcn_global_load_lds((gu32*)g, (lu32*)l, 16, 0, 0);
}

// ---------- prep: x fp32->bf16 (blocks 0..4095) + weight transposes ----------
struct TJob { const float* src; u16* dst; int K, N, ldt, row_off, blk0; };
struct TJobs { TJob j[7]; };

__global__ __launch_bounds__(256) void prep_kernel(const float* __restrict__ x,
                                                   u16* __restrict__ xb, TJobs jobs) {
  int bid = blockIdx.x;
  int tid = threadIdx.x;
  if (bid < 4096) {
    int i = (bid * 256 + tid) * 4;
    float4 v = *reinterpret_cast<const float4*>(x + i);
    union { u16 h[4]; unsigned long long ll; } pk;
    pk.h[0] = f2b(v.x); pk.h[1] = f2b(v.y); pk.h[2] = f2b(v.z); pk.h[3] = f2b(v.w);
    *reinterpret_cast<unsigned long long*>(xb + i) = pk.ll;
    return;
  }
  bid -= 4096;
  __shared__ float tile[32][33];
  int ji = 0;
  #pragma unroll
  for (int i = 6; i > 0; --i)
    if (bid >= jobs.j[i].blk0) { ji = i; break; }
  const TJob jb = jobs.j[ji];
  int local = bid - jb.blk0;
  int nb = jb.N >> 5;
  int n0 = (local % nb) * 32, k0 = (local / nb) * 32;
  int cx = tid & 31, ry = tid >> 5;
  #pragma unroll
  for (int i = 0; i < 4; i++)
    tile[ry + i * 8][cx] = jb.src[(size_t)(k0 + ry + i * 8) * jb.N + n0 + cx];
  __syncthreads();
  #pragma unroll
  for (int i = 0; i < 4; i++)
    jb.dst[(size_t)(jb.row_off + n0 + ry + i * 8) * jb.ldt + k0 + cx] =
        f2b(tile[cx][ry + i * 8]);
}

// ---------- GEMM: 8 waves, MTx128 tile, BK=64, swizzled LDS ----------
// mode: 0 bf16 out; 1 f32 out; 2/3 rope on cols>=1024 then bf16 out
struct GJob { const u16* A; const u16* Bt; void* C; int lda, ldb, ldc, K, mode; };

template<int ID, int MT>
__global__ __launch_bounds__(512) void gemm_k(GJob j0, GJob j1, int split,
                                              const float* __restrict__ cosT,
                                              const float* __restrict__ sinT) {
  constexpr int MR = MT / 64;            // acc rows per wave (2 or 1)
  __shared__ u16 As[2][MT * 64];
  __shared__ u16 Bs[2][128 * 64];
  const bool first = (int)blockIdx.x < split;
  const GJob jb = first ? j0 : j1;
  const int bx = blockIdx.x - (first ? 0 : split);
  const int tid = threadIdx.x;
  const int wave = tid >> 6, lane = tid & 63;
  const int wr = wave >> 1, wc = wave & 1;   // wave grid 4(M) x 2(N)
  const int l15 = lane & 15, l4 = lane >> 4;
  const int m0 = blockIdx.y * MT, n0 = bx * 128;
  const int srow = lane >> 3;
  const int scol = ((lane & 7) ^ srow) * 8;  // pre-swizzled source col

  f32x4 acc[MR][4];
  const f32x4 fzero = {0.f, 0.f, 0.f, 0.f};
  #pragma unroll
  for (int m = 0; m < MR; m++)
    #pragma unroll
    for (int n = 0; n < 4; n++)
      acc[m][n] = fzero;

  const u16* gA = jb.A + (size_t)(m0 + (MT == 128 ? wave * 16 : wave * 8) + srow) * jb.lda + scol;
  const u16* gB = jb.Bt + (size_t)(n0 + wave * 16 + srow) * jb.ldb + scol;

  auto stage = [&](int buf, int k0) {
    if constexpr (MT == 128) {
      gl_lds16(gA + k0,                      &As[buf][(wave * 16) * 64]);
      gl_lds16(gA + (size_t)8 * jb.lda + k0, &As[buf][(wave * 16 + 8) * 64]);
    } else {
      gl_lds16(gA + k0, &As[buf][(wave * 8) * 64]);
    }
    gl_lds16(gB + k0,                      &Bs[buf][(wave * 16) * 64]);
    gl_lds16(gB + (size_t)8 * jb.ldb + k0, &Bs[buf][(wave * 16 + 8) * 64]);
  };

  stage(0, 0);
  int buf = 0;
  const int K = jb.K;
  for (int k0 = 0; k0 < K; k0 += 64) {
    asm volatile("s_waitcnt vmcnt(0)" ::: "memory");
    __builtin_amdgcn_s_barrier();
    if (k0 + 64 < K) stage(buf ^ 1, k0 + 64);
    bf16x8 af[MR][2], bfr[4][2];
    #pragma unroll
    for (int m = 0; m < MR; m++) {
      const int row = wr * (MT / 4) + m * 16 + l15;
      const int xm = (row & 7) * 8;
      af[m][0] = *reinterpret_cast<const bf16x8*>(&As[buf][row * 64 + ((l4 * 8) ^ xm)]);
      af[m][1] = *reinterpret_cast<const bf16x8*>(&As[buf][row * 64 + ((32 + l4 * 8) ^ xm)]);
    }
    #pragma unroll
    for (int n = 0; n < 4; n++) {
      const int row = wc * 64 + n * 16 + l15;
      const int xm = (row & 7) * 8;
      bfr[n][0] = *reinterpret_cast<const bf16x8*>(&Bs[buf][row * 64 + ((l4 * 8) ^ xm)]);
      bfr[n][1] = *reinterpret_cast<const bf16x8*>(&Bs[buf][row * 64 + ((32 + l4 * 8) ^ xm)]);
    }
    #pragma unroll
    for (int m = 0; m < MR; m++)
      #pragma unroll
      for (int n = 0; n < 4; n++) {
        acc[m][n] = __builtin_amdgcn_mfma_f32_16x16x32_bf16(af[m][0], bfr[n][0], acc[m][n], 0, 0, 0);
        acc[m][n] = __builtin_amdgcn_mfma_f32_16x16x32_bf16(af[m][1], bfr[n][1], acc[m][n], 0, 0, 0);
      }
    buf ^= 1;
  }

  const int row_base = m0 + wr * (MT / 4) + l4 * 4;
  const int col_base = n0 + wc * 64 + l15;
  const int mode = jb.mode;
  const int ldc = jb.ldc;

  if (mode == 1) {
    float* Cf = (float*)jb.C;
    #pragma unroll
    for (int m = 0; m < MR; m++)
      #pragma unroll
      for (int n = 0; n < 4; n++)
        #pragma unroll
        for (int r = 0; r < 4; r++)
          Cf[(size_t)(row_base + m * 16 + r) * ldc + col_base + n * 16] = acc[m][n][r];
    return;
  }

  if (mode >= 2 && (n0 + wc * 64) >= 1024) {
    #pragma unroll
    for (int m = 0; m < MR; m++)
      #pragma unroll
      for (int r = 0; r < 4; r++) {
        int t = (row_base + m * 16 + r) & (T_ - 1);
        const float* cp = cosT + t * 64 + l15;
        const float* sp = sinT + t * 64 + l15;
        float c0 = cp[0], c16 = cp[16], c32 = cp[32], c48 = cp[48];
        float s0 = sp[0], s16 = sp[16], s32 = sp[32], s48 = sp[48];
        float x0 = acc[m][0][r], x1 = acc[m][1][r];
        float x2 = acc[m][2][r], x3 = acc[m][3][r];
        acc[m][0][r] = x0 * c0 - x2 * s0;
        acc[m][1][r] = x1 * c16 - x3 * s16;
        acc[m][2][r] = x2 * c32 + x0 * s32;
        acc[m][3][r] = x3 * c48 + x1 * s48;
      }
  }

  u16* Cb = (u16*)jb.C;
  #pragma unroll
  for (int m = 0; m < MR; m++)
    #pragma unroll
    for (int n = 0; n < 4; n++)
      #pragma unroll
      for (int r = 0; r < 4; r++)
        Cb[(size_t)(row_base + m * 16 + r) * ldc + col_base + n * 16] = f2b(acc[m][n][r]);
}

// ---------- VT transpose: kvo V-cols [4096][0..1024) -> VT[b][col][t] ----------
__global__ __launch_bounds__(256) void vtrans_kernel(const u16* __restrict__ kvo,
                                                     u16* __restrict__ vt) {
  __shared__ u16 tile[64][72];
  const int tid = threadIdx.x;
  const int cb = blockIdx.x * 64;
  const int rb = blockIdx.y * 64;
  const int b = rb >> 11, t0 = rb & 2047;
  const int rr = tid >> 3;
  const int c8 = (tid & 7) * 8;
  #pragma unroll
  for (int i = 0; i < 2; i++) {
    int r = i * 32 + rr;
    uint4 v = *reinterpret_cast<const uint4*>(kvo + (size_t)(rb + r) * 2048 + cb + c8);
    *reinterpret_cast<uint4*>(&tile[r][c8]) = v;
  }
  __syncthreads();
  #pragma unroll
  for (int i = 0; i < 2; i++) {
    int c = i * 32 + rr;
    int r8 = c8;
    union { u16 h[8]; uint4 v; } pk;
    #pragma unroll
    for (int j = 0; j < 8; j++) pk.h[j] = tile[r8 + j][c];
    *reinterpret_cast<uint4*>(&vt[(size_t)(b * 1024 + cb + c) * 2048 + t0 + r8]) = pk.v;
  }
}

// ---------- causal flash attention: QBLK=128, 8 waves, PV via 16x16x16 ----------
__global__ __launch_bounds__(512) void attn_kernel(const u16* __restrict__ qo,
                                                   const u16* __restrict__ kvo,
                                                   const u16* __restrict__ vtg,
                                                   u16* __restrict__ yb) {
  __shared__ u16 K_lds[2][64 * 128];   // rows swizzled: byte ^= (row&7)<<4
  __shared__ u16 V_lds[2][64 * 64];    // V^T, same swizzle
  const int tid = threadIdx.x;
  const int wave = tid >> 6, lane = tid & 63;
  const int l15 = lane & 15, l4 = lane >> 4;
  const int bid = blockIdx.x;
  const int bh = bid & 31;
  const int qi = 15 - (bid >> 5);      // LPT: heaviest first
  const int b = bh >> 4, h = bh & 15;
  const int q0 = qi * 128;
  const int qrow = q0 + wave * 16 + l15;

  const u16* qb = qo + (size_t)(b * T_ + qrow) * 2048 + h * 64;
  bf16x8 qf[4];
  qf[0] = *reinterpret_cast<const bf16x8*>(qb + l4 * 8);
  qf[1] = *reinterpret_cast<const bf16x8*>(qb + 32 + l4 * 8);
  qf[2] = *reinterpret_cast<const bf16x8*>(qb + 1024 + l4 * 8);
  qf[3] = *reinterpret_cast<const bf16x8*>(qb + 1056 + l4 * 8);

  const u16* Kbase = kvo + (size_t)(b * T_) * 2048 + h * 64;
  const u16* Vbase = vtg + (size_t)(b * 1024 + h * 64) * 2048;

  const int krow_i = lane >> 4;
  const int kc2 = (lane & 15) * 16;
  const int vrow_i = lane >> 3;
  const int vc2 = (lane & 7) * 16;

  auto stage = [&](int buf, int kv0) {
    #pragma unroll
    for (int j = 0; j < 2; j++) {
      int row = wave * 8 + j * 4 + krow_i;
      int c2x = kc2 ^ ((row & 7) << 4);
      int cu = c2x >> 1;
      const u16* src = Kbase + (size_t)(kv0 + row) * 2048 + (cu < 64 ? cu : 960 + cu);
      gl_lds16(src, &K_lds[buf][(wave * 8 + j * 4) * 128]);
    }
    {
      int row = wave * 8 + vrow_i;
      int c2x = vc2 ^ ((row & 7) << 4);
      const u16* src = Vbase + (size_t)row * 2048 + kv0 + (c2x >> 1);
      gl_lds16(src, &V_lds[buf][(wave * 8) * 64]);
    }
  };

  const f32x4 fzero = {0.f, 0.f, 0.f, 0.f};
  f32x4 oT[4];
  #pragma unroll
  for (int f = 0; f < 4; f++) oT[f] = fzero;
  float m_run = -1e30f, l_run = 0.f;

  const float SCALE2 = 0.125f * 1.44269504f;   // 1/sqrt(64) * log2(e)
  const int nt = qi * 2 + 2;
  const int t_diag = qi * 2 + (wave >> 2);

  stage(0, 0);
  int buf = 0;

  for (int t = 0; t < nt; t++) {
    const int kv0 = t * 64;
    asm volatile("s_waitcnt vmcnt(0)" ::: "memory");
    __builtin_amdgcn_s_barrier();
    if (t + 1 < nt) stage(buf ^ 1, kv0 + 64);

    if (t <= t_diag) {
      const char* Kb = (const char*)&K_lds[buf][0];
      const char* Vb = (const char*)&V_lds[buf][0];

      f32x4 sT[4];
      #pragma unroll
      for (int c = 0; c < 4; c++) sT[c] = fzero;
      #pragma unroll
      for (int c = 0; c < 4; c++) {
        const int krow = c * 16 + l15;
        const int kxm = (krow & 7) << 4;
        #pragma unroll
        for (int s = 0; s < 4; s++) {
          bf16x8 kf = *reinterpret_cast<const bf16x8*>(
              Kb + krow * 256 + ((s * 64 + l4 * 16) ^ kxm));
          sT[c] = __builtin_amdgcn_mfma_f32_16x16x32_bf16(kf, qf[s], sT[c], 0, 0, 0);
        }
      }

      const bool diag = (t == t_diag);
      float p[4][4];
      float mx = -1e30f;
      #pragma unroll
      for (int c = 0; c < 4; c++)
        #pragma unroll
        for (int r = 0; r < 4; r++) {
          float s = sT[c][r] * SCALE2;
          if (diag) {
            int kv = kv0 + c * 16 + l4 * 4 + r;
            if (kv > qrow) s = -1e30f;
          }
          p[c][r] = s;
          mx = fmaxf(mx, s);
        }
      mx = fmaxf(mx, __shfl_xor(mx, 16));
      mx = fmaxf(mx, __shfl_xor(mx, 32));
      if (__any(mx > m_run + 11.5f)) {         // defer-max (T13)
        float m_new = fmaxf(m_run, mx);
        float corr = ex2(m_run - m_new);
        l_run *= corr;
        #pragma unroll
        for (int f = 0; f < 4; f++) oT[f] *= corr;
        m_run = m_new;
      }
      float rsum = 0.f;
      #pragma unroll
      for (int c = 0; c < 4; c++)
        #pragma unroll
        for (int r = 0; r < 4; r++) {
          float pe = ex2(p[c][r] - m_run);
          p[c][r] = pe;
          rsum += pe;
        }
      rsum += __shfl_xor(rsum, 16);
      rsum += __shfl_xor(rsum, 32);
      l_run += rsum;

      // pack P^T fragment in-register: pc[c] IS the 16x16x16 B-operand
      uint2 pc[4];
      #pragma unroll
      for (int c = 0; c < 4; c++) {
        pc[c].x = cvt_pk(p[c][0], p[c][1]);
        pc[c].y = cvt_pk(p[c][2], p[c][3]);
      }

      // PV: oT[f] += V^T(16x16 block f, kv-slice c) x P^T(slice c)
      #pragma unroll
      for (int f = 0; f < 4; f++) {
        const int vrow = f * 16 + l15;
        const int vxm = (vrow & 7) << 4;
        #pragma unroll
        for (int c = 0; c < 4; c++) {
          uint2 va = *reinterpret_cast<const uint2*>(
              Vb + vrow * 128 + ((c * 32 + l4 * 8) ^ vxm));
          mfma16(oT[f], va, pc[c]);
        }
      }
    }

    buf ^= 1;
  }

  const float inv = 1.f / l_run;
  #pragma unroll
  for (int f = 0; f < 4; f++) {
    uint2 pk2;
    pk2.x = cvt_pk(oT[f][0] * inv, oT[f][1] * inv);
    pk2.y = cvt_pk(oT[f][2] * inv, oT[f][3] * inv);
    *reinterpret_cast<uint2*>(
        &yb[(size_t)(b * T_ + qrow) * 1024 + h * 64 + f * 16 + l4 * 4]) = pk2;
  }
}

// ---------- launcher ----------
extern "C" void kernel_launch(void* const* d_in, const int* in_sizes, int n_in,
                              void* d_out, int out_size, void* d_ws, size_t ws_size,
                              hipStream_t stream) {
  const float* x         = (const float*)d_in[0];
  const float* cosT      = (const float*)d_in[1];
  const float* sinT      = (const float*)d_in[2];
  const float* W_kv_down = (const float*)d_in[3];
  const float* W_kv_up   = (const float*)d_in[4];
  const float* W_k_rope  = (const float*)d_in[5];
  const float* W_q_down  = (const float*)d_in[6];
  const float* W_q_up    = (const float*)d_in[7];
  const float* W_q_rope  = (const float*)d_in[8];
  const float* W_out     = (const float*)d_in[9];
  float* out = (float*)d_out;
  char* ws = (char*)d_ws;

  u16* xb    = (u16*)(ws + 0);              // 4096x1024 (reused as yb)
  u16* lat   = (u16*)(ws + 8388608);        // 4096x640
  u16* WdT   = (u16*)(ws + 13631488);       // 640x1024
  u16* WkvT  = (u16*)(ws + 14942208);       // 2048x256
  u16* WqT   = (u16*)(ws + 15990784);       // 2048x384
  u16* WoutT = (u16*)(ws + 17563648);       // 1024x1024
  u16* kvo   = (u16*)(ws + 19660800);       // 4096x2048 (kv_up | k_rope)
  u16* qo    = (u16*)(ws + 36438016);       // 4096x2048 (q_up | q_rope)
  u16* VT    = (u16*)(ws + 53215232);       // [2][1024][2048] V^T
  u16* yb    = (u16*)(ws + 0);

  TJobs jobs;
  jobs.j[0] = {W_kv_down, WdT,   1024, 256,  1024, 0,    0};
  jobs.j[1] = {W_q_down,  WdT,   1024, 384,  1024, 256,  256};
  jobs.j[2] = {W_kv_up,   WkvT,  256,  1024, 256,  0,    640};
  jobs.j[3] = {W_k_rope,  WkvT,  256,  1024, 256,  1024, 896};
  jobs.j[4] = {W_q_up,    WqT,   384,  1024, 384,  0,    1152};
  jobs.j[5] = {W_q_rope,  WqT,   384,  1024, 384,  1024, 1536};
  jobs.j[6] = {W_out,     WoutT, 1024, 1024, 1024, 0,    1920};
  prep_kernel<<<7040, 256, 0, stream>>>(x, xb, jobs);

  // gemm1: lat = xb @ [W_kv_down | W_q_down]  (MT=64 -> 320 blocks)
  GJob g1 = {xb, WdT, lat, 1024, 1024, 640, 1024, 0};
  gemm_k<0, 64><<<dim3(5, 64), 512, 0, stream>>>(g1, g1, 5, nullptr, nullptr);

  // gemm2+3 fused: kvo = lat[:,:256]@[W_kv_up|W_k_rope] ; qo = lat[:,256:]@[W_q_up|W_q_rope]
  GJob g2 = {lat,       WkvT, kvo, 640, 256, 2048, 256, 2};
  GJob g3 = {lat + 256, WqT,  qo,  640, 384, 2048, 384, 3};
  gemm_k<1, 128><<<dim3(32, 32), 512, 0, stream>>>(g2, g3, 16, cosT, sinT);

  // VT = transpose of kvo's V-content columns (coalesced)
  vtrans_kernel<<<dim3(16, 64), 256, 0, stream>>>(kvo, VT);

  attn_kernel<<<512, 512, 0, stream>>>(qo, kvo, VT, yb);

  // gemm4: out = yb @ W_out (fp32, MT=64 -> 512 blocks)
  GJob g4 = {yb, WoutT, out, 1024, 1024, 1024, 1024, 1};
  gemm_k<2, 64><<<dim3(8, 64), 512, 0, stream>>>(g4, g4, 8, nullptr, nullptr);
}